// Round 9
// baseline (522.321 us; speedup 1.0000x reference)
//
#include <hip/hip_runtime.h>

#define DIM 64

// ---- bucket-scatter CSR build parameters ----
#define SPAN 256            // nodes per bucket
#define NSHIFT 8            // log2(SPAN)
#define MAXNB 2048          // max buckets (nn <= 524288)
#define BCAP 8192           // records per bucket region (item-bucket mean ~5120 + ~43 sigma)
#define EPT 16              // edges per thread in pass A
#define EPB (256 * EPT)     // edges per block in pass A (4096 -> 8192 records, LDS-staged)

typedef __attribute__((ext_vector_type(4))) _Float16 half4;
typedef __attribute__((ext_vector_type(8))) _Float16 half8;

// ---------- CSR build, pass A: bucket the directed edge records ----------
// Single edge read: records + bucket-ids staged in LDS during the histogram
// pass, then drained to rec[] via per-bucket LDS cursors.
// Record: (dst & 255) | (src << 8); src < 2^19 -> fits 27 bits.
__global__ void bucket_scatter3(const int* __restrict__ rows, const int* __restrict__ cols,
                                int* __restrict__ bucket_cnt, int* __restrict__ rec,
                                int nu, int nb, int E) {
    __shared__ int   hist[MAXNB];       // 8 KB: histogram -> global write cursor
    __shared__ int   lrec[2 * EPB];     // 32 KB packed records
    __shared__ short lbid[2 * EPB];     // 16 KB bucket ids
    int t = threadIdx.x;
    for (int b = t; b < MAXNB; b += 256) hist[b] = 0;
    __syncthreads();
    int e0 = blockIdx.x * EPB;
    int ne = min(e0 + EPB, E) - e0;
    // phase 1: read edges ONCE; histogram + stash
    for (int k = t; k < ne; k += 256) {
        int r = rows[e0 + k];
        int c = nu + cols[e0 + k];
        int b1 = r >> NSHIFT, b2 = c >> NSHIFT;
        atomicAdd(&hist[b1], 1);
        atomicAdd(&hist[b2], 1);
        lrec[2 * k]     = (r & (SPAN - 1)) | (c << NSHIFT);
        lbid[2 * k]     = (short)b1;
        lrec[2 * k + 1] = (c & (SPAN - 1)) | (r << NSHIFT);
        lbid[2 * k + 1] = (short)b2;
    }
    __syncthreads();
    // phase 2: reserve chunk per touched bucket; hist becomes the cursor
    for (int b = t; b < nb; b += 256) {
        int h = hist[b];
        int off = 0;
        if (h) off = atomicAdd(&bucket_cnt[b * 16], h);
        if (off + h > BCAP) off = BCAP - h;  // stay in-region (statistically unreachable; h<=BCAP)
        hist[b] = b * BCAP + off;
    }
    __syncthreads();
    // phase 3: drain LDS records to global
    int nr = 2 * ne;
    for (int k = t; k < nr; k += 256) {
        int b = lbid[k];
        int pos = atomicAdd(&hist[b], 1);
        rec[pos] = lrec[k];
    }
}

// ---------- CSR build, pass B: scan bucket sizes -> global bases ----------
// 1024 threads x 2 elements covers nb <= 2048.
__global__ void bucket_scan(const int* __restrict__ bucket_cnt, int* __restrict__ bucket_base,
                            int* __restrict__ row_ptr_end, int nb) {
    __shared__ int lds[1024];
    int t = threadIdx.x;
    int i0 = 2 * t, i1 = 2 * t + 1;
    int v0 = (i0 < nb) ? min(bucket_cnt[i0 * 16], BCAP) : 0;
    int v1 = (i1 < nb) ? min(bucket_cnt[i1 * 16], BCAP) : 0;
    int s = v0 + v1;
    lds[t] = s; __syncthreads();
    for (int off = 1; off < 1024; off <<= 1) {
        int add = (t >= off) ? lds[t - off] : 0;
        __syncthreads();
        lds[t] += add;
        __syncthreads();
    }
    int excl = lds[t] - s;
    if (i0 < nb) bucket_base[i0] = excl;
    if (i1 < nb) bucket_base[i1] = excl + v0;
    if (i0 == nb - 1) *row_ptr_end = excl + v0;
    if (i1 == nb - 1) *row_ptr_end = excl + v0 + v1;
}

// ---------- CSR build, pass C: per-bucket deg histogram + scan + place ----------
// Single rec read pass (stash in LDS while histogramming); node-level scan
// via wave shfl (2 barriers); placement reads LDS.
__global__ void bucket_fill4(const int* __restrict__ bucket_cnt, const int* __restrict__ bucket_base,
                             const int* __restrict__ rec, int* __restrict__ colidx,
                             int* __restrict__ row_ptr, int nn) {
    __shared__ int lrec[BCAP];   // 32 KB staged records
    __shared__ int cnt[SPAN];    // histogram -> per-node start offset
    __shared__ int pc[SPAN];     // placement counters
    __shared__ int wsum[4];
    int t = threadIdx.x;
    int b = blockIdx.x;
    int nrec = min(bucket_cnt[b * 16], BCAP);
    const int* r0 = rec + (size_t)b * BCAP;
    int gbase = bucket_base[b];

    cnt[t] = 0;                  // SPAN == blockDim == 256
    __syncthreads();
    // single global read: stash + degree histogram
    for (int i = t; i < nrec; i += 256) {
        int v = r0[i];
        lrec[i] = v;
        atomicAdd(&cnt[v & (SPAN - 1)], 1);
    }
    __syncthreads();
    // exclusive scan of cnt: inclusive wave scan + cross-wave offsets
    int d = cnt[t];
    int lane = t & 63, wv = t >> 6;
    int x = d;
#pragma unroll
    for (int off = 1; off < 64; off <<= 1) {
        int y = __shfl_up(x, off, 64);
        if (lane >= off) x += y;
    }
    if (lane == 63) wsum[wv] = x;
    __syncthreads();
    int wpre = 0;
#pragma unroll
    for (int k = 0; k < 3; k++) if (k < wv) wpre += wsum[k];
    int excl = wpre + x - d;
    int node = (b << NSHIFT) + t;
    if (node < nn) row_ptr[node] = gbase + excl;
    cnt[t] = excl;
    pc[t] = 0;
    __syncthreads();
    // place records from LDS
    for (int i = t; i < nrec; i += 256) {
        int v = lrec[i];
        int dl = v & (SPAN - 1);
        int pos = gbase + cnt[dl] + atomicAdd(&pc[dl], 1);
        colidx[pos] = v >> NSHIFT;
    }
}

// ---------- pre-scale: x0 = dinv ⊙ ego (fp16); deg from row_ptr deltas ----------
__global__ void prescale_kernel(const float4* __restrict__ ue, const float4* __restrict__ ie,
                                const int* __restrict__ row_ptr, half4* __restrict__ xp,
                                int nu, int nn) {
    size_t i = (size_t)blockIdx.x * blockDim.x + threadIdx.x;
    if (i >= (size_t)nn * 16) return;
    int node = (int)(i >> 4);
    float4 v = (node < nu) ? ue[i] : ie[i - (size_t)nu * 16];
    int d = row_ptr[node + 1] - row_ptr[node];
    float dn = rsqrtf(1e-7f + (float)d);
    half4 h;
    h.x = (_Float16)(v.x * dn); h.y = (_Float16)(v.y * dn);
    h.z = (_Float16)(v.z * dn); h.w = (_Float16)(v.w * dn);
    xp[i] = h;
}

// ---------- fused gather-SpMM + cosine reweight + acc ----------
// 8 lanes per node, 8 nodes per wave.  Inner loop: 8 edges/iter with 8
// independent packed-fp16 accumulator chains (fully unrolled, compile-time
// indices) -> ~8 x 128 B gathers in flight per wave, reaching the
// bandwidth-delay product that the 4-deep version missed (latency-bound at
// HBM 47%, VALU 21%).  Epilogue amortized over 8 nodes/wave as before.
// EGO16: cosine operand is the fp16 prescaled x0 row (dinv cancels):
//   w = dot(x,x0) / (max(|x|,eps) * max(|x0|, eps*dn))
template<bool EGO16>
__global__ void spmm_fused(const int* __restrict__ row_ptr, const int* __restrict__ colidx,
                           const half8* __restrict__ xp, const half8* __restrict__ x0,
                           const float4* __restrict__ eu, const float4* __restrict__ ei,
                           half8* __restrict__ xn, float4* __restrict__ acc,
                           int nu, int nn, int first, int last) {
    int gid  = (int)(blockIdx.x * blockDim.x + threadIdx.x) >> 3;  // node index
    int li   = threadIdx.x & 7;                                    // 16-B chunk in row
    bool valid = gid < nn;
    int node = valid ? gid : nn - 1;
    int start = row_ptr[node];
    int deg   = row_ptr[node + 1] - start;

    const half8 hz = {(_Float16)0, (_Float16)0, (_Float16)0, (_Float16)0,
                      (_Float16)0, (_Float16)0, (_Float16)0, (_Float16)0};
    half8 a[8];
#pragma unroll
    for (int k = 0; k < 8; k++) a[k] = hz;
    const unsigned li16 = (unsigned)li << 4;
    const char* xpb = (const char*)xp;
    int j = 0;
    // full 8-edge steps: 8 colidx dwords + 8 dwordx4 gathers issued before
    // any dependent add (all indices compile-time after unroll)
    for (; j + 8 <= deg; j += 8) {
        int s[8];
#pragma unroll
        for (int k = 0; k < 8; k++) s[k] = colidx[start + j + k];
#pragma unroll
        for (int k = 0; k < 8; k++)
            a[k] += *(const half8*)(xpb + (((unsigned)s[k] << 7) + li16));
    }
    // single predicated 8-wide tail
    if (j < deg) {
#pragma unroll
        for (int k = 0; k < 8; k++) {
            if (j + k < deg) {
                int sk = colidx[start + j + k];
                a[k] += *(const half8*)(xpb + (((unsigned)sk << 7) + li16));
            }
        }
    }
    a[0] += a[1]; a[2] += a[3]; a[4] += a[5]; a[6] += a[7];
    a[0] += a[2]; a[4] += a[6];
    a[0] += a[4];

    float dn = rsqrtf(1e-7f + (float)deg);
    float xv[8];
#pragma unroll
    for (int k = 0; k < 8; k++) xv[k] = (float)a[0][k] * dn;

    float ev[8];
    if constexpr (EGO16) {
        half8 e = *(const half8*)((const char*)x0 + (((size_t)node << 7) + li16));
#pragma unroll
        for (int k = 0; k < 8; k++) ev[k] = (float)e[k];
    } else {
        size_t o32 = (size_t)node * 16 + 2 * li;
        float4 e0 = (node < nu) ? eu[o32] : ei[o32 - (size_t)nu * 16];
        float4 e1 = (node < nu) ? eu[o32 + 1] : ei[o32 + 1 - (size_t)nu * 16];
        ev[0] = e0.x; ev[1] = e0.y; ev[2] = e0.z; ev[3] = e0.w;
        ev[4] = e1.x; ev[5] = e1.y; ev[6] = e1.z; ev[7] = e1.w;
    }
    float dp = 0.f, np = 0.f, ep = 0.f;
#pragma unroll
    for (int k = 0; k < 8; k++) {
        dp += xv[k] * ev[k];
        np += xv[k] * xv[k];
        ep += ev[k] * ev[k];
    }
    // reduce within the 8-lane group (masks stay inside the group)
#pragma unroll
    for (int m = 1; m <= 4; m <<= 1) {
        dp += __shfl_xor(dp, m, 64);
        np += __shfl_xor(np, m, 64);
        ep += __shfl_xor(ep, m, 64);
    }
    float en = EGO16 ? fmaxf(sqrtf(ep), 1e-8f * dn) : fmaxf(sqrtf(ep), 1e-8f);
    float w = dp / (fmaxf(sqrtf(np), 1e-8f) * en);

    if (valid) {
        if (!last) {
            half8 h;
#pragma unroll
            for (int k = 0; k < 8; k++) h[k] = (_Float16)(w * xv[k] * dn);
            *(half8*)((char*)xn + (((size_t)node << 7) + li16)) = h;
        }
        size_t o = (size_t)node * 16 + 2 * li;
        float4 f0 = make_float4(w * xv[0], w * xv[1], w * xv[2], w * xv[3]);
        float4 f1 = make_float4(w * xv[4], w * xv[5], w * xv[6], w * xv[7]);
        if (first) {
            acc[o] = f0;
            acc[o + 1] = f1;
        } else {
            float4 t0 = acc[o], t1 = acc[o + 1];
            acc[o]     = make_float4(t0.x + f0.x, t0.y + f0.y, t0.z + f0.z, t0.w + f0.w);
            acc[o + 1] = make_float4(t1.x + f1.x, t1.y + f1.y, t1.z + f1.z, t1.w + f1.w);
        }
    }
}

extern "C" void kernel_launch(void* const* d_in, const int* in_sizes, int n_in,
                              void* d_out, int out_size, void* d_ws, size_t ws_size,
                              hipStream_t stream) {
    const float* uemb = (const float*)d_in[0];
    const float* iemb = (const float*)d_in[1];
    const int*   rows = (const int*)d_in[2];
    const int*   cols = (const int*)d_in[3];
    // d_in[4] = n_layers; fixed at 3 (identical work per call required)

    const int nu = in_sizes[0] / DIM;
    const int ni = in_sizes[1] / DIM;
    const int E  = in_sizes[2];
    const int nn = nu + ni;
    const int nb = (nn + SPAN - 1) >> NSHIFT;   // buckets (<= MAXNB for nn <= 524288)

    // ---- workspace layout ----
    const size_t hbuf = (size_t)nn * 16 * sizeof(half4);     // 128 B/node
    const size_t rec_bytes = (size_t)nb * BCAP * sizeof(int);
    const size_t bufB = hbuf > rec_bytes ? hbuf : rec_bytes;
    const size_t cid_bytes = (size_t)2 * E * sizeof(int);
    const size_t rp_bytes  = (size_t)(nn + 1) * sizeof(int);
    const size_t bc_bytes  = (size_t)MAXNB * 16 * sizeof(int);
    const size_t bb_bytes  = (size_t)MAXNB * sizeof(int);
    const size_t need3 = hbuf + bufB + hbuf + cid_bytes + rp_bytes + bc_bytes + bb_bytes + 1024;
    const bool ego16 = (ws_size >= need3);   // 3-buffer fp16-ego path if ws allows

    char* ws = (char*)d_ws;
    half4* A = (half4*)ws;                       // x0 = prescaled ego (fp16)
    half4* B = (half4*)(ws + hbuf);              // xn buffer 1 (aliases rec during build)
    half4* C = nullptr;
    char* after;
    if (ego16) { C = (half4*)(ws + hbuf + bufB); after = ws + hbuf + bufB + hbuf; }
    else       { after = ws + hbuf + bufB; }
    int* colidx   = (int*)after;
    int* row_ptr  = (int*)(after + cid_bytes);
    int* bkt_cnt  = (int*)(after + cid_bytes + rp_bytes);
    int* bkt_base = (int*)(after + cid_bytes + rp_bytes + bc_bytes);
    int* rec      = (int*)B;

    // ---- build normalized CSR: 3 kernels, zero random global atomics ----
    hipMemsetAsync(bkt_cnt, 0, bc_bytes, stream);
    bucket_scatter3<<<(E + EPB - 1) / EPB, 256, 0, stream>>>(rows, cols, bkt_cnt, rec, nu, nb, E);
    bucket_scan<<<1, 1024, 0, stream>>>(bkt_cnt, bkt_base, row_ptr + nn, nb);
    bucket_fill4<<<nb, 256, 0, stream>>>(bkt_cnt, bkt_base, rec, colidx, row_ptr, nn);

    // ---- prescale layer-0 input (full-grid; deg from row_ptr deltas) ----
    {
        size_t thr = (size_t)nn * 16;
        prescale_kernel<<<(unsigned)((thr + 255) / 256), 256, 0, stream>>>(
            (const float4*)uemb, (const float4*)iemb, row_ptr, A, nu, nn);
    }

    // ---- 3 fused SpMM+reweight layers (8 lanes/node, 8 nodes/wave) ----
    unsigned gs = (unsigned)(((size_t)nn * 8 + 255) / 256);
    float4* out = (float4*)d_out;
    if (ego16) {
        spmm_fused<true><<<gs, 256, 0, stream>>>(row_ptr, colidx, (const half8*)A, (const half8*)A,
                                                 nullptr, nullptr, (half8*)B, out, nu, nn, 1, 0);
        spmm_fused<true><<<gs, 256, 0, stream>>>(row_ptr, colidx, (const half8*)B, (const half8*)A,
                                                 nullptr, nullptr, (half8*)C, out, nu, nn, 0, 0);
        spmm_fused<true><<<gs, 256, 0, stream>>>(row_ptr, colidx, (const half8*)C, (const half8*)A,
                                                 nullptr, nullptr, nullptr, out, nu, nn, 0, 1);
    } else {
        spmm_fused<false><<<gs, 256, 0, stream>>>(row_ptr, colidx, (const half8*)A, nullptr,
                                                  (const float4*)uemb, (const float4*)iemb,
                                                  (half8*)B, out, nu, nn, 1, 0);
        spmm_fused<false><<<gs, 256, 0, stream>>>(row_ptr, colidx, (const half8*)B, nullptr,
                                                  (const float4*)uemb, (const float4*)iemb,
                                                  (half8*)A, out, nu, nn, 0, 0);
        spmm_fused<false><<<gs, 256, 0, stream>>>(row_ptr, colidx, (const half8*)A, nullptr,
                                                  (const float4*)uemb, (const float4*)iemb,
                                                  nullptr, out, nu, nn, 0, 1);
    }
}

// Round 11
// 489.336 us; speedup vs baseline: 1.0674x; 1.0674x over previous
//
#include <hip/hip_runtime.h>

#define DIM 64

// ---- bucket-scatter CSR build parameters ----
#define SPAN 256            // nodes per bucket
#define NSHIFT 8            // log2(SPAN)
#define MAXNB 2048          // max buckets (nn <= 524288)
#define BCAP 8192           // records per bucket region (item-bucket mean ~5120 + ~43 sigma)
#define EPT 16              // edges per thread in pass A
#define EPB (256 * EPT)     // edges per block in pass A (4096 -> 8192 records, LDS-staged)

typedef __attribute__((ext_vector_type(4))) _Float16 half4;
typedef __attribute__((ext_vector_type(8))) _Float16 half8;

// ---------- CSR build, pass A: bucket the directed edge records ----------
// Single edge read: records + bucket-ids staged in LDS during the histogram
// pass, then drained to rec[] via per-bucket LDS cursors.
// Record: (dst & 255) | (src << 8); src < 2^19 -> fits 27 bits.
__global__ void bucket_scatter3(const int* __restrict__ rows, const int* __restrict__ cols,
                                int* __restrict__ bucket_cnt, int* __restrict__ rec,
                                int nu, int nb, int E) {
    __shared__ int   hist[MAXNB];       // 8 KB: histogram -> global write cursor
    __shared__ int   lrec[2 * EPB];     // 32 KB packed records
    __shared__ short lbid[2 * EPB];     // 16 KB bucket ids
    int t = threadIdx.x;
    for (int b = t; b < MAXNB; b += 256) hist[b] = 0;
    __syncthreads();
    int e0 = blockIdx.x * EPB;
    int ne = min(e0 + EPB, E) - e0;
    // phase 1: read edges ONCE; histogram + stash
    for (int k = t; k < ne; k += 256) {
        int r = rows[e0 + k];
        int c = nu + cols[e0 + k];
        int b1 = r >> NSHIFT, b2 = c >> NSHIFT;
        atomicAdd(&hist[b1], 1);
        atomicAdd(&hist[b2], 1);
        lrec[2 * k]     = (r & (SPAN - 1)) | (c << NSHIFT);
        lbid[2 * k]     = (short)b1;
        lrec[2 * k + 1] = (c & (SPAN - 1)) | (r << NSHIFT);
        lbid[2 * k + 1] = (short)b2;
    }
    __syncthreads();
    // phase 2: reserve chunk per touched bucket; hist becomes the cursor
    for (int b = t; b < nb; b += 256) {
        int h = hist[b];
        int off = 0;
        if (h) off = atomicAdd(&bucket_cnt[b * 16], h);
        if (off + h > BCAP) off = BCAP - h;  // stay in-region (statistically unreachable; h<=BCAP)
        hist[b] = b * BCAP + off;
    }
    __syncthreads();
    // phase 3: drain LDS records to global
    int nr = 2 * ne;
    for (int k = t; k < nr; k += 256) {
        int b = lbid[k];
        int pos = atomicAdd(&hist[b], 1);
        rec[pos] = lrec[k];
    }
}

// ---------- CSR build, pass B: scan bucket sizes -> global bases ----------
// 1024 threads x 2 elements covers nb <= 2048.
__global__ void bucket_scan(const int* __restrict__ bucket_cnt, int* __restrict__ bucket_base,
                            int* __restrict__ row_ptr_end, int nb) {
    __shared__ int lds[1024];
    int t = threadIdx.x;
    int i0 = 2 * t, i1 = 2 * t + 1;
    int v0 = (i0 < nb) ? min(bucket_cnt[i0 * 16], BCAP) : 0;
    int v1 = (i1 < nb) ? min(bucket_cnt[i1 * 16], BCAP) : 0;
    int s = v0 + v1;
    lds[t] = s; __syncthreads();
    for (int off = 1; off < 1024; off <<= 1) {
        int add = (t >= off) ? lds[t - off] : 0;
        __syncthreads();
        lds[t] += add;
        __syncthreads();
    }
    int excl = lds[t] - s;
    if (i0 < nb) bucket_base[i0] = excl;
    if (i1 < nb) bucket_base[i1] = excl + v0;
    if (i0 == nb - 1) *row_ptr_end = excl + v0;
    if (i1 == nb - 1) *row_ptr_end = excl + v0 + v1;
}

// ---------- CSR build, pass C: per-bucket deg histogram + scan + place ----------
// Single rec read pass (stash in LDS while histogramming); node-level scan
// via wave shfl (2 barriers); placement reads LDS.
__global__ void bucket_fill4(const int* __restrict__ bucket_cnt, const int* __restrict__ bucket_base,
                             const int* __restrict__ rec, int* __restrict__ colidx,
                             int* __restrict__ row_ptr, int nn) {
    __shared__ int lrec[BCAP];   // 32 KB staged records
    __shared__ int cnt[SPAN];    // histogram -> per-node start offset
    __shared__ int pc[SPAN];     // placement counters
    __shared__ int wsum[4];
    int t = threadIdx.x;
    int b = blockIdx.x;
    int nrec = min(bucket_cnt[b * 16], BCAP);
    const int* r0 = rec + (size_t)b * BCAP;
    int gbase = bucket_base[b];

    cnt[t] = 0;                  // SPAN == blockDim == 256
    __syncthreads();
    // single global read: stash + degree histogram
    for (int i = t; i < nrec; i += 256) {
        int v = r0[i];
        lrec[i] = v;
        atomicAdd(&cnt[v & (SPAN - 1)], 1);
    }
    __syncthreads();
    // exclusive scan of cnt: inclusive wave scan + cross-wave offsets
    int d = cnt[t];
    int lane = t & 63, wv = t >> 6;
    int x = d;
#pragma unroll
    for (int off = 1; off < 64; off <<= 1) {
        int y = __shfl_up(x, off, 64);
        if (lane >= off) x += y;
    }
    if (lane == 63) wsum[wv] = x;
    __syncthreads();
    int wpre = 0;
#pragma unroll
    for (int k = 0; k < 3; k++) if (k < wv) wpre += wsum[k];
    int excl = wpre + x - d;
    int node = (b << NSHIFT) + t;
    if (node < nn) row_ptr[node] = gbase + excl;
    cnt[t] = excl;
    pc[t] = 0;
    __syncthreads();
    // place records from LDS
    for (int i = t; i < nrec; i += 256) {
        int v = lrec[i];
        int dl = v & (SPAN - 1);
        int pos = gbase + cnt[dl] + atomicAdd(&pc[dl], 1);
        colidx[pos] = v >> NSHIFT;
    }
}

// ---------- pre-scale: x0 = dinv ⊙ ego (fp16); deg from row_ptr deltas ----------
__global__ void prescale_kernel(const float4* __restrict__ ue, const float4* __restrict__ ie,
                                const int* __restrict__ row_ptr, half4* __restrict__ xp,
                                int nu, int nn) {
    size_t i = (size_t)blockIdx.x * blockDim.x + threadIdx.x;
    if (i >= (size_t)nn * 16) return;
    int node = (int)(i >> 4);
    float4 v = (node < nu) ? ue[i] : ie[i - (size_t)nu * 16];
    int d = row_ptr[node + 1] - row_ptr[node];
    float dn = rsqrtf(1e-7f + (float)d);
    half4 h;
    h.x = (_Float16)(v.x * dn); h.y = (_Float16)(v.y * dn);
    h.z = (_Float16)(v.z * dn); h.w = (_Float16)(v.w * dn);
    xp[i] = h;
}

// ---------- fused gather-SpMM + cosine reweight + acc ----------
// 8 lanes per node, 8 nodes per wave; 4-edge inner step with 4 independent
// packed-fp16 accumulator chains (R9 showed 8-deep gains nothing: the kernel
// sits at the ~4 TB/s L2-miss fill ceiling -> only byte reduction helps).
// ACC16: layer-sum accumulator held fp16 in workspace; last layer reads it
// and writes the final fp32 output fused (saves 153.6 MB across 3 layers).
// EGO16: cosine operand is the fp16 prescaled x0 row (dinv cancels):
//   w = dot(x,x0) / (max(|x|,eps) * max(|x0|, eps*dn))
template<bool EGO16, bool ACC16>
__global__ void spmm_fused(const int* __restrict__ row_ptr, const int* __restrict__ colidx,
                           const half8* __restrict__ xp, const half8* __restrict__ x0,
                           const float4* __restrict__ eu, const float4* __restrict__ ei,
                           half8* __restrict__ xn, half8* __restrict__ accH,
                           float4* __restrict__ outF,
                           int nu, int nn, int first, int last) {
    int gid  = (int)(blockIdx.x * blockDim.x + threadIdx.x) >> 3;  // node index
    int li   = threadIdx.x & 7;                                    // 16-B chunk in row
    bool valid = gid < nn;
    int node = valid ? gid : nn - 1;
    int start = row_ptr[node];
    int deg   = row_ptr[node + 1] - start;

    const half8 hz = {(_Float16)0, (_Float16)0, (_Float16)0, (_Float16)0,
                      (_Float16)0, (_Float16)0, (_Float16)0, (_Float16)0};
    half8 a0 = hz, a1 = hz, a2 = hz, a3 = hz;
    const unsigned li16 = (unsigned)li << 4;
    const char* xpb = (const char*)xp;
    int j = 0;
    for (; j + 4 <= deg; j += 4) {
        int s0 = colidx[start + j];
        int s1 = colidx[start + j + 1];
        int s2 = colidx[start + j + 2];
        int s3 = colidx[start + j + 3];
        a0 += *(const half8*)(xpb + (((unsigned)s0 << 7) + li16));
        a1 += *(const half8*)(xpb + (((unsigned)s1 << 7) + li16));
        a2 += *(const half8*)(xpb + (((unsigned)s2 << 7) + li16));
        a3 += *(const half8*)(xpb + (((unsigned)s3 << 7) + li16));
    }
    if (j < deg) {
        int laste = start + deg - 1;
        int s0 = colidx[start + j];
        int s1 = colidx[min(start + j + 1, laste)];
        int s2 = colidx[min(start + j + 2, laste)];
        a0 += *(const half8*)(xpb + (((unsigned)s0 << 7) + li16));
        if (j + 1 < deg) a1 += *(const half8*)(xpb + (((unsigned)s1 << 7) + li16));
        if (j + 2 < deg) a2 += *(const half8*)(xpb + (((unsigned)s2 << 7) + li16));
    }
    a0 += a1; a2 += a3; a0 += a2;

    float dn = rsqrtf(1e-7f + (float)deg);
    float xv[8];
#pragma unroll
    for (int k = 0; k < 8; k++) xv[k] = (float)a0[k] * dn;

    float ev[8];
    if constexpr (EGO16) {
        half8 e = *(const half8*)((const char*)x0 + (((size_t)node << 7) + li16));
#pragma unroll
        for (int k = 0; k < 8; k++) ev[k] = (float)e[k];
    } else {
        size_t o32 = (size_t)node * 16 + 2 * li;
        float4 e0 = (node < nu) ? eu[o32] : ei[o32 - (size_t)nu * 16];
        float4 e1 = (node < nu) ? eu[o32 + 1] : ei[o32 + 1 - (size_t)nu * 16];
        ev[0] = e0.x; ev[1] = e0.y; ev[2] = e0.z; ev[3] = e0.w;
        ev[4] = e1.x; ev[5] = e1.y; ev[6] = e1.z; ev[7] = e1.w;
    }
    float dp = 0.f, np = 0.f, ep = 0.f;
#pragma unroll
    for (int k = 0; k < 8; k++) {
        dp += xv[k] * ev[k];
        np += xv[k] * xv[k];
        ep += ev[k] * ev[k];
    }
    // reduce within the 8-lane group (masks stay inside the group)
#pragma unroll
    for (int m = 1; m <= 4; m <<= 1) {
        dp += __shfl_xor(dp, m, 64);
        np += __shfl_xor(np, m, 64);
        ep += __shfl_xor(ep, m, 64);
    }
    float en = EGO16 ? fmaxf(sqrtf(ep), 1e-8f * dn) : fmaxf(sqrtf(ep), 1e-8f);
    float w = dp / (fmaxf(sqrtf(np), 1e-8f) * en);
    float yv[8];
#pragma unroll
    for (int k = 0; k < 8; k++) yv[k] = w * xv[k];

    if (valid) {
        size_t ob = ((size_t)node << 7) + li16;   // byte offset in half8-row buffers
        if (!last) {
            half8 h;
#pragma unroll
            for (int k = 0; k < 8; k++) h[k] = (_Float16)(yv[k] * dn);
            *(half8*)((char*)xn + ob) = h;
        }
        if constexpr (ACC16) {
            if (first) {
                half8 h;
#pragma unroll
                for (int k = 0; k < 8; k++) h[k] = (_Float16)yv[k];
                *(half8*)((char*)accH + ob) = h;
            } else if (!last) {
                half8 p = *(const half8*)((const char*)accH + ob);
                half8 h;
#pragma unroll
                for (int k = 0; k < 8; k++) h[k] = (_Float16)((float)p[k] + yv[k]);
                *(half8*)((char*)accH + ob) = h;
            } else {
                half8 p = *(const half8*)((const char*)accH + ob);
                size_t o = (size_t)node * 16 + 2 * li;
                outF[o]     = make_float4((float)p[0] + yv[0], (float)p[1] + yv[1],
                                          (float)p[2] + yv[2], (float)p[3] + yv[3]);
                outF[o + 1] = make_float4((float)p[4] + yv[4], (float)p[5] + yv[5],
                                          (float)p[6] + yv[6], (float)p[7] + yv[7]);
            }
        } else {
            size_t o = (size_t)node * 16 + 2 * li;
            float4 f0 = make_float4(yv[0], yv[1], yv[2], yv[3]);
            float4 f1 = make_float4(yv[4], yv[5], yv[6], yv[7]);
            if (first) {
                outF[o] = f0;
                outF[o + 1] = f1;
            } else {
                float4 t0 = outF[o], t1 = outF[o + 1];
                outF[o]     = make_float4(t0.x + f0.x, t0.y + f0.y, t0.z + f0.z, t0.w + f0.w);
                outF[o + 1] = make_float4(t1.x + f1.x, t1.y + f1.y, t1.z + f1.z, t1.w + f1.w);
            }
        }
    }
}

extern "C" void kernel_launch(void* const* d_in, const int* in_sizes, int n_in,
                              void* d_out, int out_size, void* d_ws, size_t ws_size,
                              hipStream_t stream) {
    const float* uemb = (const float*)d_in[0];
    const float* iemb = (const float*)d_in[1];
    const int*   rows = (const int*)d_in[2];
    const int*   cols = (const int*)d_in[3];
    // d_in[4] = n_layers; fixed at 3 (identical work per call required)

    const int nu = in_sizes[0] / DIM;
    const int ni = in_sizes[1] / DIM;
    const int E  = in_sizes[2];
    const int nn = nu + ni;
    const int nb = (nn + SPAN - 1) >> NSHIFT;   // buckets (<= MAXNB for nn <= 524288)

    // ---- workspace layout ----
    const size_t hbuf = (size_t)nn * 16 * sizeof(half4);     // 128 B/node
    const size_t rec_bytes = (size_t)nb * BCAP * sizeof(int);
    const size_t bufB = hbuf > rec_bytes ? hbuf : rec_bytes; // slot big enough for rec
    const size_t cid_bytes = (size_t)2 * E * sizeof(int);
    const size_t rp_bytes  = (size_t)(nn + 1) * sizeof(int);
    const size_t bc_bytes  = (size_t)MAXNB * 16 * sizeof(int);
    const size_t bb_bytes  = (size_t)MAXNB * sizeof(int);
    const size_t tail = cid_bytes + rp_bytes + bc_bytes + bb_bytes + 1024;
    const size_t need4 = 3 * hbuf + bufB + tail;   // A,B,C + acc16 slot(=rec home)
    const size_t need3 = 2 * hbuf + bufB + tail;   // A,C + B slot(=rec home)
    const bool acc16 = (ws_size >= need4);
    const bool ego16 = (ws_size >= need3);

    char* ws = (char*)d_ws;
    half4 *A = nullptr, *B = nullptr, *C = nullptr, *D = nullptr;
    char* after;
    int* rec;
    if (acc16) {
        A = (half4*)ws;                    // x0 = prescaled ego (fp16)
        B = (half4*)(ws + hbuf);           // xn buffer 1
        C = (half4*)(ws + 2 * hbuf);       // xn buffer 2
        D = (half4*)(ws + 3 * hbuf);       // acc16 (aliases rec during build)
        rec = (int*)D;
        after = ws + 3 * hbuf + bufB;
    } else if (ego16) {
        A = (half4*)ws;
        B = (half4*)(ws + hbuf);           // xn buffer 1 (aliases rec during build)
        C = (half4*)(ws + hbuf + bufB);
        rec = (int*)B;
        after = ws + 2 * hbuf + bufB;
    } else {
        A = (half4*)ws;
        B = (half4*)(ws + hbuf);           // aliases rec
        rec = (int*)B;
        after = ws + hbuf + bufB;
    }
    int* colidx   = (int*)after;
    int* row_ptr  = (int*)(after + cid_bytes);
    int* bkt_cnt  = (int*)(after + cid_bytes + rp_bytes);
    int* bkt_base = (int*)(after + cid_bytes + rp_bytes + bc_bytes);

    // ---- build normalized CSR: 3 kernels, zero random global atomics ----
    hipMemsetAsync(bkt_cnt, 0, bc_bytes, stream);
    bucket_scatter3<<<(E + EPB - 1) / EPB, 256, 0, stream>>>(rows, cols, bkt_cnt, rec, nu, nb, E);
    bucket_scan<<<1, 1024, 0, stream>>>(bkt_cnt, bkt_base, row_ptr + nn, nb);
    bucket_fill4<<<nb, 256, 0, stream>>>(bkt_cnt, bkt_base, rec, colidx, row_ptr, nn);

    // ---- prescale layer-0 input (full-grid; deg from row_ptr deltas) ----
    {
        size_t thr = (size_t)nn * 16;
        prescale_kernel<<<(unsigned)((thr + 255) / 256), 256, 0, stream>>>(
            (const float4*)uemb, (const float4*)iemb, row_ptr, A, nu, nn);
    }

    // ---- 3 fused SpMM+reweight layers (8 lanes/node, 8 nodes/wave) ----
    unsigned gs = (unsigned)(((size_t)nn * 8 + 255) / 256);
    float4* out = (float4*)d_out;
    if (acc16) {
        spmm_fused<true, true><<<gs, 256, 0, stream>>>(row_ptr, colidx, (const half8*)A, (const half8*)A,
                                                       nullptr, nullptr, (half8*)B, (half8*)D, out,
                                                       nu, nn, 1, 0);
        spmm_fused<true, true><<<gs, 256, 0, stream>>>(row_ptr, colidx, (const half8*)B, (const half8*)A,
                                                       nullptr, nullptr, (half8*)C, (half8*)D, out,
                                                       nu, nn, 0, 0);
        spmm_fused<true, true><<<gs, 256, 0, stream>>>(row_ptr, colidx, (const half8*)C, (const half8*)A,
                                                       nullptr, nullptr, nullptr, (half8*)D, out,
                                                       nu, nn, 0, 1);
    } else if (ego16) {
        spmm_fused<true, false><<<gs, 256, 0, stream>>>(row_ptr, colidx, (const half8*)A, (const half8*)A,
                                                        nullptr, nullptr, (half8*)B, nullptr, out,
                                                        nu, nn, 1, 0);
        spmm_fused<true, false><<<gs, 256, 0, stream>>>(row_ptr, colidx, (const half8*)B, (const half8*)A,
                                                        nullptr, nullptr, (half8*)C, nullptr, out,
                                                        nu, nn, 0, 0);
        spmm_fused<true, false><<<gs, 256, 0, stream>>>(row_ptr, colidx, (const half8*)C, (const half8*)A,
                                                        nullptr, nullptr, nullptr, nullptr, out,
                                                        nu, nn, 0, 1);
    } else {
        spmm_fused<false, false><<<gs, 256, 0, stream>>>(row_ptr, colidx, (const half8*)A, nullptr,
                                                         (const float4*)uemb, (const float4*)iemb,
                                                         (half8*)B, nullptr, out, nu, nn, 1, 0);
        spmm_fused<false, false><<<gs, 256, 0, stream>>>(row_ptr, colidx, (const half8*)B, nullptr,
                                                         (const float4*)uemb, (const float4*)iemb,
                                                         (half8*)A, nullptr, out, nu, nn, 0, 0);
        spmm_fused<false, false><<<gs, 256, 0, stream>>>(row_ptr, colidx, (const half8*)A, nullptr,
                                                         (const float4*)uemb, (const float4*)iemb,
                                                         nullptr, nullptr, out, nu, nn, 0, 1);
    }
}